// Round 5
// baseline (1805.547 us; speedup 1.0000x reference)
//
#include <hip/hip_runtime.h>
#include <hip/hip_bf16.h>

// Problem constants
constexpr int NB  = 16;     // batch
constexpr int DIN = 512;    // channels
constexpr int TT  = 4096;   // time
constexpr int NCB = 9;      // codebooks
constexpr int KK  = 1024;   // entries per codebook

// output layout (FLOAT32: codes, latent, closs, bloss)
constexpr size_t OUT_LAT   = (size_t)NB * NCB * TT;            // 589824
constexpr size_t OUT_CLOSS = OUT_LAT + (size_t)NB * DIN * TT;  // 34144256

constexpr int SRES = 516;   // s_res row stride (mult of 4 for b128; 2-way banks = free)

// Scratch as __device__ globals (never trust ws_size).
__device__ __align__(16) float g_cbn [NCB * KK * 8];
__device__ __align__(16) float g_c2  [NCB * KK];
__device__ __align__(16) float g_win [NCB * 8 * DIN];   // [i][o][c]
__device__ __align__(16) float g_wout[NCB * DIN * 8];   // [i][c][d]
__device__ double g_loss;

// square with forced separate rounding (numpy rounds every square before sums;
// blocks -ffp-contract=fast from fusing the mul into a following add)
__device__ __forceinline__ float sqf(float x) {
  float r = x * x;
  asm volatile("" : "+v"(r));
  return r;
}

// ---------- combined prep (one launch): codebooks, out-proj WN, in-proj WN ----------
__global__ void prep_all_k(const float* __restrict__ in_v, const float* __restrict__ in_g,
                           const float* __restrict__ out_v, const float* __restrict__ out_g,
                           const float* __restrict__ cb) {
  const int bid = blockIdx.x, tid = threadIdx.x;
  if (bid < 36) {
    // normalized codebooks + squared norms (np tree-of-8); zero loss
    const int row = bid * 256 + tid;  // i*1024 + k, < 9216
    const float* v = cb + (size_t)row * 8;
    float q[8];
#pragma unroll
    for (int d = 0; d < 8; ++d) q[d] = sqf(v[d]);
    float nrm = sqrtf(((q[0] + q[1]) + (q[2] + q[3])) + ((q[4] + q[5]) + (q[6] + q[7])));
    nrm = fmaxf(nrm, 1e-12f);
    float cn[8];
#pragma unroll
    for (int d = 0; d < 8; ++d) { cn[d] = v[d] / nrm; g_cbn[(size_t)row * 8 + d] = cn[d]; }
    float s2[8];
#pragma unroll
    for (int d = 0; d < 8; ++d) s2[d] = sqf(cn[d]);
    g_c2[row] = ((s2[0] + s2[1]) + (s2[2] + s2[3])) + ((s2[4] + s2[5]) + (s2[6] + s2[7]));
    if (row == 0) g_loss = 0.0;
  } else if (bid < 54) {
    // out-proj weight-norm (n=8 norm: np unrolled-8 tree)
    const int row = (bid - 36) * 256 + tid;  // i*512 + c, < 4608
    const float* v = out_v + (size_t)row * 8;
    float q[8];
#pragma unroll
    for (int d = 0; d < 8; ++d) q[d] = sqf(v[d]);
    const float nrm = sqrtf(((q[0] + q[1]) + (q[2] + q[3])) + ((q[4] + q[5]) + (q[6] + q[7])));
    const float g = out_g[row];
    float* w = g_wout + (size_t)row * 8;
#pragma unroll
    for (int d = 0; d < 8; ++d) w[d] = (g * v[d]) / nrm;
  } else {
    // in-proj weight-norm: EXACT numpy pairwise_sum(512): 4×128 blocks, each
    // 8 scalar accumulators r[j]+=s[8m+j], tree-of-8; blocks (B0+B1)+(B2+B3).
    const int r = tid;  // i*8 + o
    if (r >= NCB * 8) return;
    const float* v = in_v + (size_t)r * DIN;
    float blk[4];
#pragma unroll
    for (int bb = 0; bb < 4; ++bb) {
      const float* a = v + bb * 128;
      float r8[8];
#pragma unroll
      for (int j = 0; j < 8; ++j) r8[j] = sqf(a[j]);
#pragma unroll
      for (int m = 1; m < 16; ++m)
#pragma unroll
        for (int j = 0; j < 8; ++j) r8[j] += sqf(a[m * 8 + j]);
      blk[bb] = ((r8[0] + r8[1]) + (r8[2] + r8[3])) + ((r8[4] + r8[5]) + (r8[6] + r8[7]));
    }
    const float total = (blk[0] + blk[1]) + (blk[2] + blk[3]);
    const float nrm = sqrtf(total);
    const float g = in_g[r];
    float* w = g_win + (size_t)r * DIN;
    for (int c = 0; c < DIN; ++c) w[c] = (g * v[c]) / nrm;  // np: (g*v) rounds, then /
  }
}

// ---------- main fused RVQ chain ----------
// 1 block = 16 columns, 256 threads. LDS 34 KB -> 4 blocks/CU.
// Per step: [bar] A1(64thr dual-chain) [bar] B(all, in-wave argmin) [bar] D(all).
__global__ __launch_bounds__(256, 4)
void rvq_main_k(const float* __restrict__ z, const float* __restrict__ in_b,
                const float* __restrict__ out_b, const float* __restrict__ cb,
                float* __restrict__ out) {
  __shared__ __align__(16) float s_res[16 * SRES];  // residual [col][c]
  __shared__ float s_ze[128];   // z_e [d][col]
  __shared__ float s_zq[128];   // z_q_st [d][col]

  const int tid = threadIdx.x;
  const int col = tid & 15;     // D/init ownership: column
  const int cg  = tid >> 4;     // 0..15: channel group; owns c = 2*cg + 32*p + {0,1}
  const int bcol = tid >> 4;    // B ownership: column
  const int ksb  = tid & 15;    // B: k-subset (k = 16j + ksb)
  const int b   = blockIdx.x >> 8;
  const int t0  = (blockIdx.x & 255) << 4;

  // init: residual = z (exact copy); latent accumulators zero.
  float lr[32];
  {
    const float* zb = z + (size_t)b * DIN * TT + t0 + col;
#pragma unroll
    for (int p = 0; p < 16; ++p) {
      const int c0 = 2 * cg + 32 * p;
      const float v0 = zb[(size_t)c0 * TT];
      const float v1 = zb[(size_t)(c0 + 1) * TT];
      *(float2*)(s_res + col * SRES + c0) = make_float2(v0, v1);
      lr[2 * p] = 0.0f; lr[2 * p + 1] = 0.0f;
    }
  }

  float loss_acc = 0.0f;

  for (int i = 0; i < NCB; ++i) {
    __syncthreads();  // orders init/D(i-1) s_res writes & D's s_zq reads vs A1/B(i)

    // ---- A1: in-proj. 64 threads, each runs TWO serial FMA chains (o, o+4)
    // over c=0..511 ascending — bit-identical to np einsum SOP. r from LDS
    // b128 (read once per 2 chains), W_in from global (L1/L2-hot, VMEM pipe idle).
    if (tid < 64) {
      const int cc = tid & 15, og = tid >> 4;  // og 0..3
      const float4* rr  = (const float4*)(s_res + cc * SRES);
      const float4* w0p = (const float4*)(g_win + (size_t)(i * 8 + og) * DIN);
      const float4* w1p = (const float4*)(g_win + (size_t)(i * 8 + og + 4) * DIN);
      float a0 = 0.0f, a1 = 0.0f;
#pragma unroll 4
      for (int h = 0; h < 128; ++h) {
        const float4 r  = rr[h];
        const float4 w0 = w0p[h];
        const float4 w1 = w1p[h];
        a0 = fmaf(w0.x, r.x, a0); a0 = fmaf(w0.y, r.y, a0);
        a0 = fmaf(w0.z, r.z, a0); a0 = fmaf(w0.w, r.w, a0);
        a1 = fmaf(w1.x, r.x, a1); a1 = fmaf(w1.y, r.y, a1);
        a1 = fmaf(w1.z, r.z, a1); a1 = fmaf(w1.w, r.w, a1);
      }
      s_ze[og * 16 + cc]       = a0 + in_b[i * 8 + og];
      s_ze[(og + 4) * 16 + cc] = a1 + in_b[i * 8 + og + 4];
    }
    __syncthreads();

    // ---- B: normalize (inline, duplicated per thread — identical ops) +
    // distance scan (k = 16j+ksb) + in-wave argmin butterfly over the 16
    // lanes of each column group (lex (d,k) min == np first-min).
    {
      float e[8], q[8];
#pragma unroll
      for (int d = 0; d < 8; ++d) { e[d] = s_ze[d * 16 + bcol]; q[d] = sqf(e[d]); }
      float nrm = sqrtf(((q[0] + q[1]) + (q[2] + q[3])) + ((q[4] + q[5]) + (q[6] + q[7])));
      nrm = fmaxf(nrm, 1e-12f);
      float en[8], s2[8];
#pragma unroll
      for (int d = 0; d < 8; ++d) { en[d] = e[d] / nrm; s2[d] = sqf(en[d]); }
      const float sv = ((s2[0] + s2[1]) + (s2[2] + s2[3])) + ((s2[4] + s2[5]) + (s2[6] + s2[7]));

      const float4* cp4 = (const float4*)(g_cbn + (size_t)i * 8192 + (ksb << 3));
      const float* c2p  = g_c2 + i * KK + ksb;
      float dmin = 3.402823466e38f; int kmin = 0;
#pragma unroll 4
      for (int j = 0; j < 64; ++j) {
        const float4 c0 = cp4[j * 32];
        const float4 c1 = cp4[j * 32 + 1];
        const float cc2 = c2p[j << 4];
        float dot = 0.0f;
        dot = fmaf(en[0], c0.x, dot); dot = fmaf(en[1], c0.y, dot);
        dot = fmaf(en[2], c0.z, dot); dot = fmaf(en[3], c0.w, dot);
        dot = fmaf(en[4], c1.x, dot); dot = fmaf(en[5], c1.y, dot);
        dot = fmaf(en[6], c1.z, dot); dot = fmaf(en[7], c1.w, dot);
        const float dist = fmaf(-2.0f, dot, sv) + cc2;  // == (s-2dot)+c2
        if (dist < dmin) { dmin = dist; kmin = (j << 4) + ksb; }  // strict <
      }
      // butterfly merge within 16-lane column group
#pragma unroll
      for (int m = 1; m < 16; m <<= 1) {
        const float od = __shfl_xor(dmin, m, 16);
        const int   ok = __shfl_xor(kmin, m, 16);
        if (od < dmin || (od == dmin && ok < kmin)) { dmin = od; kmin = ok; }
      }
      if (ksb == 0) out[((size_t)b * NCB + i) * TT + t0 + bcol] = (float)kmin;
      if (ksb < 8) {
        const int d = ksb;
        const float zq = cb[((size_t)i * KK + kmin) * 8 + d];  // RAW codebook
        const float ze = s_ze[d * 16 + bcol];
        const float df = ze - zq;
        loss_acc = fmaf(df, df, loss_acc);
        s_zq[d * 16 + bcol] = ze + (zq - ze);  // STE rounding mirrored
      }
    }
    __syncthreads();

    // ---- D: out-proj (sequential 8-FMA ascending d per channel — identical)
    // + latent & residual update; channels owned in contiguous pairs -> f2 RMW.
    {
      float qv[8];
#pragma unroll
      for (int d = 0; d < 8; ++d) qv[d] = s_zq[d * 16 + col];
      const float* gw = g_wout + (size_t)i * 4096;
      const float2* ob2 = (const float2*)(out_b + i * DIN);
#pragma unroll 4
      for (int p = 0; p < 16; ++p) {
        const int c0 = 2 * cg + 32 * p;
        const float4 wa = *(const float4*)(gw + c0 * 8);
        const float4 wb = *(const float4*)(gw + c0 * 8 + 4);
        const float4 wc = *(const float4*)(gw + c0 * 8 + 8);
        const float4 wd = *(const float4*)(gw + c0 * 8 + 12);
        float d0 = 0.0f, d1 = 0.0f;
        d0 = fmaf(wa.x, qv[0], d0); d0 = fmaf(wa.y, qv[1], d0);
        d0 = fmaf(wa.z, qv[2], d0); d0 = fmaf(wa.w, qv[3], d0);
        d0 = fmaf(wb.x, qv[4], d0); d0 = fmaf(wb.y, qv[5], d0);
        d0 = fmaf(wb.z, qv[6], d0); d0 = fmaf(wb.w, qv[7], d0);
        d1 = fmaf(wc.x, qv[0], d1); d1 = fmaf(wc.y, qv[1], d1);
        d1 = fmaf(wc.z, qv[2], d1); d1 = fmaf(wc.w, qv[3], d1);
        d1 = fmaf(wd.x, qv[4], d1); d1 = fmaf(wd.y, qv[5], d1);
        d1 = fmaf(wd.z, qv[6], d1); d1 = fmaf(wd.w, qv[7], d1);
        const float2 ob = ob2[cg + 16 * p];
        const float lat0 = d0 + ob.x;
        const float lat1 = d1 + ob.y;
        lr[2 * p] += lat0; lr[2 * p + 1] += lat1;
        float2* rp = (float2*)(s_res + col * SRES + c0);
        float2 rv = *rp;
        rv.x -= lat0; rv.y -= lat1;
        *rp = rv;
      }
    }
  }

  // latent output (per-step f32 accumulation, mirrored exactly)
  {
    float* lat = out + OUT_LAT + (size_t)b * DIN * TT + t0 + col;
#pragma unroll
    for (int p = 0; p < 16; ++p) {
      const int c0 = 2 * cg + 32 * p;
      lat[(size_t)c0 * TT]       = lr[2 * p];
      lat[(size_t)(c0 + 1) * TT] = lr[2 * p + 1];
    }
  }

  // loss reduce: full-wave shuffle, one atomic per wave
  {
    float v = loss_acc;
#pragma unroll
    for (int off = 32; off; off >>= 1) v += __shfl_down(v, off);
    if ((tid & 63) == 0) atomicAdd(&g_loss, (double)v);
  }
}

// ---------- epilogue: finalize scalar losses ----------
__global__ void rvq_epi_k(float* __restrict__ out) {
  const float m = (float)(g_loss / 524288.0);  // B*D_CB*T
  out[OUT_CLOSS]     = m;
  out[OUT_CLOSS + 1] = m;
}

extern "C" void kernel_launch(void* const* d_in, const int* in_sizes, int n_in,
                              void* d_out, int out_size, void* d_ws, size_t ws_size,
                              hipStream_t stream) {
  const float* z     = (const float*)d_in[0];
  const float* in_v  = (const float*)d_in[1];
  const float* in_g  = (const float*)d_in[2];
  const float* in_b  = (const float*)d_in[3];
  const float* out_v = (const float*)d_in[4];
  const float* out_g = (const float*)d_in[5];
  const float* out_b = (const float*)d_in[6];
  const float* cb    = (const float*)d_in[7];
  float* out = (float*)d_out;
  (void)d_ws; (void)ws_size;

  prep_all_k <<<55, 256, 0, stream>>>(in_v, in_g, out_v, out_g, cb);
  rvq_main_k <<<4096, 256, 0, stream>>>(z, in_b, out_b, cb, out);
  rvq_epi_k  <<<1, 1, 0, stream>>>(out);
}